// Round 1
// 23898.367 us; speedup vs baseline: 1.6818x; 1.6818x over previous
//
#include <hip/hip_runtime.h>
#include <stdint.h>
#include <math.h>

namespace {

constexpr int B = 256, L = 256, F = 38, H = 512, D = 512, Z = 16, NF = 20;
constexpr float LOG2PI_F = 1.8378770664093453f;
constexpr int LBZ = L * B * Z;      // 1048576
constexpr int HALF = LBZ / 2;       // 524288
constexpr int HB = H * B;           // 131072
constexpr int DB = D * B;           // 131072
constexpr int ZB = Z * B;           // 4096
constexpr int LFB = L * F * B;      // 2490368
constexpr int TC = 32;              // tail chunk (timesteps)

// ---------------- math helpers ----------------

__device__ __forceinline__ float sigmoidf_(float x) {
  return 1.0f / (1.0f + expf(-x));
}
__device__ __forceinline__ float softplusf_(float x) {
  return fmaxf(x, 0.0f) + log1pf(expf(-fabsf(x)));
}

__device__ __forceinline__ void waveReduceAtomicAdd(float* dst, float v, int tid) {
  #pragma unroll
  for (int off = 32; off > 0; off >>= 1) v += __shfl_down(v, off, 64);
  if ((tid & 63) == 0) atomicAdd(dst, v);
}

// ---------------- threefry2x32 (JAX-compatible) ----------------

__host__ __device__ inline uint32_t rotl32_(uint32_t x, int d) {
  return (x << d) | (x >> (32 - d));
}

__host__ __device__ inline void threefry2x32_(uint32_t k0, uint32_t k1,
                                              uint32_t x0, uint32_t x1,
                                              uint32_t& o0, uint32_t& o1) {
  const uint32_t ks2 = k0 ^ k1 ^ 0x1BD11BDAu;
  uint32_t v0 = x0 + k0;
  uint32_t v1 = x1 + k1;
#define TF_RND(r) { v0 += v1; v1 = rotl32_(v1, r); v1 ^= v0; }
  TF_RND(13) TF_RND(15) TF_RND(26) TF_RND(6)
  v0 += k1;  v1 += ks2 + 1u;
  TF_RND(17) TF_RND(29) TF_RND(16) TF_RND(24)
  v0 += ks2; v1 += k0 + 2u;
  TF_RND(13) TF_RND(15) TF_RND(26) TF_RND(6)
  v0 += k0;  v1 += k1 + 3u;
  TF_RND(17) TF_RND(29) TF_RND(16) TF_RND(24)
  v0 += k1;  v1 += ks2 + 4u;
  TF_RND(13) TF_RND(15) TF_RND(26) TF_RND(6)
  v0 += ks2; v1 += k0 + 5u;
#undef TF_RND
  o0 = v0; o1 = v1;
}

__device__ __forceinline__ float erfinv_f_(float x) {
  float w = -log1pf(-x * x);
  float p;
  if (w < 5.0f) {
    w -= 2.5f;
    p = 2.81022636e-08f;
    p = fmaf(p, w, 3.43273939e-07f);
    p = fmaf(p, w, -3.5233877e-06f);
    p = fmaf(p, w, -4.39150654e-06f);
    p = fmaf(p, w, 0.00021858087f);
    p = fmaf(p, w, -0.00125372503f);
    p = fmaf(p, w, -0.00417768164f);
    p = fmaf(p, w, 0.246640727f);
    p = fmaf(p, w, 1.50140941f);
  } else {
    w = sqrtf(w) - 3.0f;
    p = -0.000200214257f;
    p = fmaf(p, w, 0.000100950558f);
    p = fmaf(p, w, 0.00134934322f);
    p = fmaf(p, w, -0.00367342844f);
    p = fmaf(p, w, 0.00573950773f);
    p = fmaf(p, w, -0.0076224613f);
    p = fmaf(p, w, 0.00943887047f);
    p = fmaf(p, w, 1.00167406f);
    p = fmaf(p, w, 2.83297682f);
  }
  return p * x;
}

__device__ __forceinline__ float bits_to_normal_(uint32_t bits) {
  uint32_t m = (bits >> 9) | 0x3f800000u;
  float f = __uint_as_float(m) - 1.0f;
  float u = f * 2.0f + (-0.99999994f);
  u = fmaxf(-0.99999994f, u);
  return 1.41421356f * erfinv_f_(u);
}

// planar flows for one batch column (per-lane), returns logdet; zv updated in place
__device__ __forceinline__ float flows_dev(float zv[Z], const float* __restrict__ pu,
                                           const float* __restrict__ pw,
                                           const float* __restrict__ pb) {
  float ld = 0.0f;
  for (int f = 0; f < NF; ++f) {
    const float* w = pw + f * Z;
    const float* u = pu + f * Z;
    float wn2 = 0.0f, wu = 0.0f;
    #pragma unroll
    for (int i = 0; i < Z; ++i) { wn2 = fmaf(w[i], w[i], wn2); wu = fmaf(w[i], u[i], wu); }
    float coef = (softplusf_(wu) - 1.0f - wu) / wn2;
    float a_in = pb[f];
    #pragma unroll
    for (int i = 0; i < Z; ++i) a_in = fmaf(zv[i], w[i], a_in);
    float a = tanhf(a_in);
    float uw = 0.0f;
    #pragma unroll
    for (int i = 0; i < Z; ++i) {
      float uh = fmaf(coef, w[i], u[i]);
      uw = fmaf(uh, w[i], uw);
      zv[i] = fmaf(uh, a, zv[i]);
    }
    ld += logf(fabsf(1.0f + (1.0f - a * a) * uw) + 1e-12f);
  }
  return ld;
}

// ---------------- small utility kernels ----------------

__global__ __launch_bounds__(256) void k_transpose_x(const float* __restrict__ x,
                                                     float* __restrict__ xT) {
  int idx = blockIdx.x * blockDim.x + threadIdx.x;  // over B*L*F
  int f = idx % F;
  int t = (idx / F) % L;
  int b = idx / (F * L);
  xT[(t * F + f) * B + b] = x[idx];
}

__global__ __launch_bounds__(256) void k_noise(float* __restrict__ eps_z,
                                               float* __restrict__ kld_acc,
                                               uint32_t kz0, uint32_t kz1,
                                               uint32_t kp0, uint32_t kp1) {
  int i = blockIdx.x * blockDim.x + threadIdx.x;  // [0, HALF)
  uint32_t a0, a1, b0, b1;
  threefry2x32_(kz0, kz1, (uint32_t)i, (uint32_t)(i + HALF), a0, a1);
  float ez0 = bits_to_normal_(a0);
  float ez1 = bits_to_normal_(a1);
  eps_z[i] = ez0;
  eps_z[i + HALF] = ez1;
  threefry2x32_(kp0, kp1, (uint32_t)i, (uint32_t)(i + HALF), b0, b1);
  float ep0 = bits_to_normal_(b0);
  float ep1 = bits_to_normal_(b1);
  float local = -0.5f * (ez0 * ez0 + ez1 * ez1) + 0.5f * (ep0 * ep0 + ep1 * ep1);
  waveReduceAtomicAdd(kld_acc, local, threadIdx.x);
}

__global__ void k_finalize(const float* __restrict__ acc, float* __restrict__ out) {
  out[(size_t)B * L * F] = acc[1];      // recon
  out[(size_t)B * L * F + 1] = acc[0];  // kld
}

// ---------------- weight composition (once per launch) ----------------
// Wc[r][k] = sum_j A[r][j] * W2[j][k]; bc[r] = sum_j A[r][j]*b2[j] + bA[r]
// One block per row r; 256 threads cover k and k+256.
__global__ __launch_bounds__(256) void k_compose(
    const float* __restrict__ A, const float* __restrict__ bA,
    const float* __restrict__ W2, const float* __restrict__ b2,
    float* __restrict__ Wc, float* __restrict__ bc) {
  const int r = blockIdx.x;
  const int k = threadIdx.x;
  float acc0 = 0.f, acc1 = 0.f;
  for (int j = 0; j < D; ++j) {
    float a = A[(size_t)r * D + j];          // wave-uniform
    acc0 = fmaf(a, W2[(size_t)j * D + k], acc0);
    acc1 = fmaf(a, W2[(size_t)j * D + k + 256], acc1);
  }
  Wc[(size_t)r * D + k] = acc0;
  Wc[(size_t)r * D + k + 256] = acc1;
  float accb = 0.f;
  for (int j = k; j < D; j += 256) accb += A[(size_t)r * D + j] * b2[j];
  __shared__ float s[256];
  s[k] = accb;
  __syncthreads();
  for (int off = 128; off > 0; off >>= 1) {
    if (k < off) s[k] += s[k + off];
    __syncthreads();
  }
  if (k == 0) bc[r] = s[0] + bA[r];
}

// ---------------- fused dual-GRU kernel ----------------
// Block: 4 waves x 64 lanes. Lanes = batch columns. Block owns 8 output rows.
// K split: wave0 does x/z-part + w0h h-rows; waves 1..3 split the rest.
// Weight fetches are wave-uniform float4 -> s_load_dwordx4. Cross-wave reduce
// through LDS with fused GRU gate epilogue.
// THETA: wave0 runs planar flows in registers (z-input); blockIdx.x==0
// publishes z_t and the -logdet kld term.
// One launch can run the phi-GRU of step t (blockIdx.z==0) concurrently with
// the theta-GRU of step t-1 (blockIdx.z==1) -- independent work.

struct GruArgs {
  const float* xin;   // THETA: z0T [Z][B]; else xT_t [F][B]
  const float* hT;    // [H][B] previous hidden
  const float* Wih;   // [3H][K1]
  const float* Whh;   // [3H][H]
  const float* bih;
  const float* bhh;
  float* hout;        // [H][B]
  float* zT_out;
  const float* pu;
  const float* pw;
  const float* pb;
  float* kld_acc;
  int w0h;            // h-rows for wave0 (rest split by 3; all bounds %4==0)
};

template<bool THETA>
__device__ __forceinline__ void gru_dev(const GruArgs& A,
                                        float (&red)[4][4][8][64]) {
  const int tid = threadIdx.x;
  const int lane = tid & 63;
  const int wv = __builtin_amdgcn_readfirstlane(tid >> 6);
  const int j0 = blockIdx.x * 8;
  const int b0 = blockIdx.y * 64;
  const int b = b0 + lane;
  constexpr int K1 = THETA ? Z : F;

  float accR[8], accZ[8], accNX[8], accNH[8];
  #pragma unroll
  for (int r = 0; r < 8; ++r) { accR[r] = 0.f; accZ[r] = 0.f; accNX[r] = 0.f; accNH[r] = 0.f; }

  float zv[Z];
  float ld = 0.0f;

  if (wv == 0) {
    const float* wr = A.Wih + (size_t)(0 * H + j0) * K1;
    const float* wz = A.Wih + (size_t)(1 * H + j0) * K1;
    const float* wn = A.Wih + (size_t)(2 * H + j0) * K1;
    if (THETA) {
      #pragma unroll
      for (int i = 0; i < Z; ++i) zv[i] = A.xin[i * B + b];
      ld = flows_dev(zv, A.pu, A.pw, A.pb);
      #pragma unroll
      for (int k = 0; k < Z; k += 4) {
        #pragma unroll
        for (int r = 0; r < 8; ++r) {
          const float4 w0 = *(const float4*)(wr + r * K1 + k);
          const float4 w1 = *(const float4*)(wz + r * K1 + k);
          const float4 w2 = *(const float4*)(wn + r * K1 + k);
          accR[r]  = fmaf(w0.x, zv[k], fmaf(w0.y, zv[k+1], fmaf(w0.z, zv[k+2], fmaf(w0.w, zv[k+3], accR[r]))));
          accZ[r]  = fmaf(w1.x, zv[k], fmaf(w1.y, zv[k+1], fmaf(w1.z, zv[k+2], fmaf(w1.w, zv[k+3], accZ[r]))));
          accNX[r] = fmaf(w2.x, zv[k], fmaf(w2.y, zv[k+1], fmaf(w2.z, zv[k+2], fmaf(w2.w, zv[k+3], accNX[r]))));
        }
      }
    } else {
      for (int k = 0; k < K1; ++k) {
        float a = A.xin[k * B + b];
        #pragma unroll
        for (int r = 0; r < 8; ++r) {
          accR[r]  = fmaf(wr[r * K1 + k], a, accR[r]);
          accZ[r]  = fmaf(wz[r * K1 + k], a, accZ[r]);
          accNX[r] = fmaf(wn[r * K1 + k], a, accNX[r]);
        }
      }
    }
  }

  // h-part (all bounds multiples of 4)
  const int rest = (H - A.w0h) / 3;
  const int hlo = (wv == 0) ? 0 : A.w0h + (wv - 1) * rest;
  const int hhi = (wv == 0) ? A.w0h : hlo + rest;
  {
    const float* vr = A.Whh + (size_t)(0 * H + j0) * H;
    const float* vz = A.Whh + (size_t)(1 * H + j0) * H;
    const float* vn = A.Whh + (size_t)(2 * H + j0) * H;
    #pragma unroll 2
    for (int k = hlo; k < hhi; k += 4) {
      const float a0 = A.hT[(size_t)(k + 0) * B + b];
      const float a1 = A.hT[(size_t)(k + 1) * B + b];
      const float a2 = A.hT[(size_t)(k + 2) * B + b];
      const float a3 = A.hT[(size_t)(k + 3) * B + b];
      #pragma unroll
      for (int r = 0; r < 8; ++r) {
        const float4 w0 = *(const float4*)(vr + (size_t)r * H + k);
        const float4 w1 = *(const float4*)(vz + (size_t)r * H + k);
        const float4 w2 = *(const float4*)(vn + (size_t)r * H + k);
        accR[r]  = fmaf(w0.x, a0, fmaf(w0.y, a1, fmaf(w0.z, a2, fmaf(w0.w, a3, accR[r]))));
        accZ[r]  = fmaf(w1.x, a0, fmaf(w1.y, a1, fmaf(w1.z, a2, fmaf(w1.w, a3, accZ[r]))));
        accNH[r] = fmaf(w2.x, a0, fmaf(w2.y, a1, fmaf(w2.z, a2, fmaf(w2.w, a3, accNH[r]))));
      }
    }
  }

  #pragma unroll
  for (int r = 0; r < 8; ++r) {
    red[wv][0][r][lane] = accR[r];
    red[wv][1][r][lane] = accZ[r];
    red[wv][2][r][lane] = accNX[r];
    red[wv][3][r][lane] = accNH[r];
  }

  if (THETA) {
    if (wv == 0 && blockIdx.x == 0) {
      #pragma unroll
      for (int i = 0; i < Z; ++i) A.zT_out[i * B + b] = zv[i];
      waveReduceAtomicAdd(A.kld_acc, -ld, lane);
    }
  }

  __syncthreads();

  #pragma unroll
  for (int it = tid; it < 512; it += 256) {
    const int r = it >> 6, l = it & 63;
    float sR = 0.f, sZ = 0.f, sNX = 0.f, sNH = 0.f;
    #pragma unroll
    for (int w = 0; w < 4; ++w) {
      sR  += red[w][0][r][l];
      sZ  += red[w][1][r][l];
      sNX += red[w][2][r][l];
      sNH += red[w][3][r][l];
    }
    const int j = j0 + r;
    const int bb = b0 + l;
    const float rg = sigmoidf_(sR + A.bih[j] + A.bhh[j]);
    const float zg = sigmoidf_(sZ + A.bih[H + j] + A.bhh[H + j]);
    const float ng = tanhf(sNX + A.bih[2 * H + j] + rg * (sNH + A.bhh[2 * H + j]));
    const float hp = A.hT[(size_t)j * B + bb];
    A.hout[(size_t)j * B + bb] = (1.0f - zg) * ng + zg * hp;
  }
}

// mode: 0 = phi only, 1 = theta only, 2 = both (blockIdx.z selects)
__global__ __launch_bounds__(256) void k_gru_dual(GruArgs phi, GruArgs th, int mode) {
  __shared__ float red[4][4][8][64];  // 32 KB
  const bool isTheta = (mode == 1) || (mode == 2 && blockIdx.z == 1);
  if (isTheta) gru_dev<true>(th, red);
  else         gru_dev<false>(phi, red);
}

// ---------------- wave-row linear kernel ----------------
// out[r][b] = act(W[r,:] . concat(A1,A2)[:,b] + bias[r]); 8 rows/block,
// K split 4 ways across waves (all split bounds %4==0), LDS reduce.
// grid.z batches over timesteps.
__global__ __launch_bounds__(256) void k_lin(
    const float* __restrict__ A1, int K1v, long sA1,
    const float* __restrict__ A2, int K2v,
    const float* __restrict__ W, const float* __restrict__ bias,
    float* __restrict__ outp, long sOut, int relu) {
  const int tid = threadIdx.x;
  const int lane = tid & 63;
  const int wv = __builtin_amdgcn_readfirstlane(tid >> 6);
  const int r0 = blockIdx.x * 8;
  const int b0 = blockIdx.y * 64;
  const int b = b0 + lane;
  const int Kv = K1v + K2v;
  const float* A1p = A1 + (size_t)blockIdx.z * sA1;
  float* outpp = outp + (size_t)blockIdx.z * sOut;
  const int klo = wv * (Kv >> 2);
  const int khi = klo + (Kv >> 2);

  float acc[8];
  #pragma unroll
  for (int r = 0; r < 8; ++r) acc[r] = 0.f;

  const float* wbase = W + (size_t)r0 * Kv;
  {
    const int hi = khi < K1v ? khi : K1v;
    #pragma unroll 4
    for (int k = klo; k < hi; k += 4) {
      const float a0 = A1p[(size_t)(k + 0) * B + b];
      const float a1 = A1p[(size_t)(k + 1) * B + b];
      const float a2 = A1p[(size_t)(k + 2) * B + b];
      const float a3 = A1p[(size_t)(k + 3) * B + b];
      #pragma unroll
      for (int r = 0; r < 8; ++r) {
        const float4 w4 = *(const float4*)(wbase + (size_t)r * Kv + k);
        acc[r] = fmaf(w4.x, a0, fmaf(w4.y, a1, fmaf(w4.z, a2, fmaf(w4.w, a3, acc[r]))));
      }
    }
  }
  if (K2v) {
    const int lo = klo > K1v ? klo : K1v;
    for (int k = lo; k < khi; k += 4) {
      const float a0 = A2[(size_t)(k - K1v + 0) * B + b];
      const float a1 = A2[(size_t)(k - K1v + 1) * B + b];
      const float a2 = A2[(size_t)(k - K1v + 2) * B + b];
      const float a3 = A2[(size_t)(k - K1v + 3) * B + b];
      #pragma unroll
      for (int r = 0; r < 8; ++r) {
        const float4 w4 = *(const float4*)(wbase + (size_t)r * Kv + k);
        acc[r] = fmaf(w4.x, a0, fmaf(w4.y, a1, fmaf(w4.z, a2, fmaf(w4.w, a3, acc[r]))));
      }
    }
  }

  __shared__ float red[4][8][64];  // 8 KB
  #pragma unroll
  for (int r = 0; r < 8; ++r) red[wv][r][lane] = acc[r];
  __syncthreads();

  #pragma unroll
  for (int it = tid; it < 512; it += 256) {
    int r = it >> 6, l = it & 63;
    float s = red[0][r][l] + red[1][r][l] + red[2][r][l] + red[3][r][l] + bias[r0 + r];
    if (relu) s = fmaxf(s, 0.f);
    outpp[(size_t)(r0 + r) * B + b0 + l] = s;
  }
}

// ---------------- z head (composed: reads h1, MLP2 folded into weights) ----
// 4 z-values per block, each with (loc,scale) row pair. K=512 split 4.
__global__ __launch_bounds__(256) void k_zhead(
    const float* __restrict__ h1T,
    const float* __restrict__ Wzl, const float* __restrict__ bzl,
    const float* __restrict__ Wzs, const float* __restrict__ bzs,
    const float* __restrict__ eps_t,   // [B][Z]
    float* __restrict__ z0T, float* __restrict__ kld_acc) {
  const int tid = threadIdx.x;
  const int lane = tid & 63;
  const int wv = __builtin_amdgcn_readfirstlane(tid >> 6);
  const int z0q = blockIdx.x * 4;
  const int b0 = blockIdx.y * 64;
  const int b = b0 + lane;
  const int klo = wv * (D >> 2), khi = klo + (D >> 2);

  const float* wp[8];
  #pragma unroll
  for (int i = 0; i < 8; ++i) {
    int zz = z0q + (i >> 1);
    wp[i] = ((i & 1) ? Wzs : Wzl) + (size_t)zz * D;
  }
  float acc[8];
  #pragma unroll
  for (int i = 0; i < 8; ++i) acc[i] = 0.f;
  #pragma unroll 4
  for (int k = klo; k < khi; k += 4) {
    const float a0 = h1T[(size_t)(k + 0) * B + b];
    const float a1 = h1T[(size_t)(k + 1) * B + b];
    const float a2 = h1T[(size_t)(k + 2) * B + b];
    const float a3 = h1T[(size_t)(k + 3) * B + b];
    #pragma unroll
    for (int i = 0; i < 8; ++i) {
      const float4 w4 = *(const float4*)(wp[i] + k);
      acc[i] = fmaf(w4.x, a0, fmaf(w4.y, a1, fmaf(w4.z, a2, fmaf(w4.w, a3, acc[i]))));
    }
  }

  __shared__ float red[4][8][64];
  #pragma unroll
  for (int i = 0; i < 8; ++i) red[wv][i][lane] = acc[i];
  __syncthreads();

  int zi = tid >> 6, l = tid & 63;
  int zz = z0q + zi;
  int bb = b0 + l;
  float sl = red[0][2 * zi][l] + red[1][2 * zi][l] + red[2][2 * zi][l] + red[3][2 * zi][l]
             + bzl[zz];
  float ss = red[0][2 * zi + 1][l] + red[1][2 * zi + 1][l] + red[2][2 * zi + 1][l]
             + red[3][2 * zi + 1][l] + bzs[zz];
  float scale = softplusf_(ss) + 1e-6f;
  float ez = eps_t[bb * Z + zz];
  z0T[zz * B + bb] = sl + scale * ez;
  waveReduceAtomicAdd(kld_acc, -logf(scale), tid);
}

// ---------------- y head (composed: reads g1, th MLP2 folded into weights) --
// 4 features per block ((loc,scale) pairs), grid.z batches timesteps.
__global__ __launch_bounds__(256) void k_yhead(
    const float* __restrict__ g1base, long sG1, int t_base,
    const float* __restrict__ Wyl, const float* __restrict__ byl,
    const float* __restrict__ Wys, const float* __restrict__ bys,
    const float* __restrict__ xT,    // [L][F][B]
    float* __restrict__ out_yloc, float* __restrict__ recon_acc) {
  const int tid = threadIdx.x;
  const int lane = tid & 63;
  const int wv = __builtin_amdgcn_readfirstlane(tid >> 6);
  const int t = t_base + blockIdx.z;
  const float* g1T = g1base + (size_t)blockIdx.z * sG1;
  const int f0 = blockIdx.x * 4;
  const int b0 = blockIdx.y * 64;
  const int b = b0 + lane;
  const int klo = wv * (D >> 2), khi = klo + (D >> 2);

  const float* wp[8];
  #pragma unroll
  for (int i = 0; i < 8; ++i) {
    int ff = f0 + (i >> 1);
    int fc = ff < F ? ff : 0;
    wp[i] = ((i & 1) ? Wys : Wyl) + (size_t)fc * D;
  }
  float acc[8];
  #pragma unroll
  for (int i = 0; i < 8; ++i) acc[i] = 0.f;
  #pragma unroll 4
  for (int k = klo; k < khi; k += 4) {
    const float a0 = g1T[(size_t)(k + 0) * B + b];
    const float a1 = g1T[(size_t)(k + 1) * B + b];
    const float a2 = g1T[(size_t)(k + 2) * B + b];
    const float a3 = g1T[(size_t)(k + 3) * B + b];
    #pragma unroll
    for (int i = 0; i < 8; ++i) {
      const float4 w4 = *(const float4*)(wp[i] + k);
      acc[i] = fmaf(w4.x, a0, fmaf(w4.y, a1, fmaf(w4.z, a2, fmaf(w4.w, a3, acc[i]))));
    }
  }

  __shared__ float red[4][8][64];
  #pragma unroll
  for (int i = 0; i < 8; ++i) red[wv][i][lane] = acc[i];
  __syncthreads();

  int fi = tid >> 6, l = tid & 63;
  int ff = f0 + fi;
  int bb = b0 + l;
  float nl = 0.0f;
  if (ff < F) {
    float loc = red[0][2 * fi][l] + red[1][2 * fi][l] + red[2][2 * fi][l] + red[3][2 * fi][l]
                + byl[ff];
    float sp = red[0][2 * fi + 1][l] + red[1][2 * fi + 1][l] + red[2][2 * fi + 1][l]
               + red[3][2 * fi + 1][l] + bys[ff];
    float scale = softplusf_(sp) + 1e-6f;
    out_yloc[((size_t)bb * L + t) * F + ff] = loc;
    float xv = xT[((size_t)t * F + ff) * B + bb];
    float d = (xv - loc) / scale;
    nl = 0.5f * d * d + logf(scale) + 0.5f * LOG2PI_F;
  }
  waveReduceAtomicAdd(recon_acc, nl, tid);
}

}  // namespace

extern "C" void kernel_launch(void* const* d_in, const int* in_sizes, int n_in,
                              void* d_out, int out_size, void* d_ws, size_t ws_size,
                              hipStream_t stream) {
  const float* x        = (const float*)d_in[0];
  const float* phi_Wih  = (const float*)d_in[1];
  const float* phi_Whh  = (const float*)d_in[2];
  const float* phi_bih  = (const float*)d_in[3];
  const float* phi_bhh  = (const float*)d_in[4];
  const float* phi_W1   = (const float*)d_in[5];
  const float* phi_b1   = (const float*)d_in[6];
  const float* phi_W2   = (const float*)d_in[7];
  const float* phi_b2   = (const float*)d_in[8];
  const float* zloc_W   = (const float*)d_in[9];
  const float* zloc_b   = (const float*)d_in[10];
  const float* zscale_W = (const float*)d_in[11];
  const float* zscale_b = (const float*)d_in[12];
  const float* pu       = (const float*)d_in[13];
  const float* pw       = (const float*)d_in[14];
  const float* pb       = (const float*)d_in[15];
  const float* th_Wih   = (const float*)d_in[16];
  const float* th_Whh   = (const float*)d_in[17];
  const float* th_bih   = (const float*)d_in[18];
  const float* th_bhh   = (const float*)d_in[19];
  const float* th_W1    = (const float*)d_in[20];
  const float* th_b1    = (const float*)d_in[21];
  const float* th_W2    = (const float*)d_in[22];
  const float* th_b2    = (const float*)d_in[23];
  const float* xloc_W   = (const float*)d_in[24];
  const float* xloc_b   = (const float*)d_in[25];
  const float* xscale_W = (const float*)d_in[26];
  const float* xscale_b = (const float*)d_in[27];

  float* out = (float*)d_out;
  float* ws = (float*)d_ws;

  // common workspace layout (floats; all offsets multiples of 16)
  float* acc   = ws;                 // [0]=kld, [1]=recon
  float* eps_z = ws + 64;            // LBZ
  float* xT    = eps_z + LBZ;        // LFB
  float* hphi0 = xT + LFB;           // HB
  float* hphi1 = hphi0 + HB;         // HB
  float* zT    = hphi1 + HB;         // ZB
  float* z0T   = zT + ZB;            // ZB
  float* h1T   = z0T + ZB;           // DB
  float* g1T   = h1T + DB;           // DB (path B theta g1)
  float* Wzl   = g1T + DB;           // Z*D
  float* Wzs   = Wzl + Z * D;        // Z*D
  float* bzl   = Wzs + Z * D;        // 64
  float* bzs   = bzl + 64;           // 64
  float* Wyl   = bzs + 64;           // F*D
  float* Wys   = Wyl + F * D;        // F*D
  float* byl   = Wys + F * D;        // 64
  float* bys   = byl + 64;           // 64
  float* tailbase = bys + 64;

  // path A: store th_h for all t, defer theta-MLP/y-head to batched tail
  size_t floatsA = (size_t)(tailbase - ws) + (size_t)(L + 1) * HB + (size_t)TC * DB;
  bool pathA = ws_size >= floatsA * sizeof(float);

  float* th_all = tailbase;                        // (L+1)*HB (path A)
  float* g1_c   = th_all + (size_t)(L + 1) * HB;   // TC*DB
  float* hth0   = tailbase;                        // path B ping-pong: th_h(even)
  float* hth1   = tailbase + HB;                   // th_h(odd); holds th_h(-1)=0

  hipMemsetAsync(acc, 0, 2 * sizeof(float), stream);
  hipMemsetAsync(hphi0, 0, (size_t)HB * sizeof(float), stream);
  hipMemsetAsync(zT, 0, (size_t)ZB * sizeof(float), stream);
  if (pathA) hipMemsetAsync(th_all, 0, (size_t)HB * sizeof(float), stream);
  else       hipMemsetAsync(hth1, 0, (size_t)HB * sizeof(float), stream);

  // JAX PRNG: key(42)=(0,42); split -> kz, kp
  uint32_t a0, a1, b0, b1;
  threefry2x32_(0u, 42u, 0u, 2u, a0, a1);
  threefry2x32_(0u, 42u, 1u, 3u, b0, b1);
  const uint32_t kz0 = a0, kz1 = b0, kp0 = a1, kp1 = b1;

  k_transpose_x<<<(B * L * F) / 256, 256, 0, stream>>>(x, xT);
  k_noise<<<HALF / 256, 256, 0, stream>>>(eps_z, acc, kz0, kz1, kp0, kp1);

  // Compose the linear MLP2 into the z/y heads (h2,g2 are linear and only
  // feed the heads): Wc = headW @ W2, bc = headW @ b2 + headb.
  k_compose<<<Z, 256, 0, stream>>>(zloc_W, zloc_b, phi_W2, phi_b2, Wzl, bzl);
  k_compose<<<Z, 256, 0, stream>>>(zscale_W, zscale_b, phi_W2, phi_b2, Wzs, bzs);
  k_compose<<<F, 256, 0, stream>>>(xloc_W, xloc_b, th_W2, th_b2, Wyl, byl);
  k_compose<<<F, 256, 0, stream>>>(xscale_W, xscale_b, th_W2, th_b2, Wys, bys);

  const dim3 gLin(D / 8, B / 64, 1);
  const dim3 gZ(Z / 4, B / 64, 1);

  // Per step, 3 chained dispatches:
  //   K1(t): [phiGRU(t) || thetaGRU(t-1)+flows]   (theta publishes z(t-1))
  //   K2(t): MLP1(t) = relu([phi_h(t); z(t-1)] @ W1^T + b1)
  //   K3(t): zhead(t) -> z0(t), kld(-log sigma)
  for (int t = 0; t <= L; ++t) {
    const bool hasPhi = (t < L);
    const bool hasTh  = (t >= 1);

    GruArgs pa = {};
    GruArgs ta = {};
    float* phi_new = (t & 1) ? hphi0 : hphi1;
    if (hasPhi) {
      pa.xin  = xT + (size_t)t * F * B;
      pa.hT   = (t & 1) ? hphi1 : hphi0;
      pa.hout = phi_new;
      pa.Wih = phi_Wih; pa.Whh = phi_Whh; pa.bih = phi_bih; pa.bhh = phi_bhh;
      pa.w0h = 92;  // wave0: 38(x) + 92(h); waves1-3: 140 each
    }
    float* th_new = nullptr;
    if (hasTh) {
      ta.xin  = z0T;  // z0(t-1)
      ta.hT   = pathA ? th_all + (size_t)(t - 1) * HB
                      : ((t & 1) ? hth1 : hth0);           // th_h(t-2)
      th_new  = pathA ? th_all + (size_t)t * HB
                      : ((t & 1) ? hth0 : hth1);           // th_h(t-1)
      ta.hout = th_new;
      ta.Wih = th_Wih; ta.Whh = th_Whh; ta.bih = th_bih; ta.bhh = th_bhh;
      ta.zT_out = zT; ta.pu = pu; ta.pw = pw; ta.pb = pb; ta.kld_acc = acc;
      ta.w0h = 80;  // wave0: flows + 16(z) + 80(h); waves1-3: 144 each
    }

    const int mode = (hasPhi && hasTh) ? 2 : (hasTh ? 1 : 0);
    dim3 gG(H / 8, B / 64, mode == 2 ? 2 : 1);
    k_gru_dual<<<gG, 256, 0, stream>>>(pa, ta, mode);

    if (hasPhi) {
      k_lin<<<gLin, 256, 0, stream>>>(phi_new, H, 0, zT, Z, phi_W1, phi_b1, h1T, 0, 1);
      k_zhead<<<gZ, 256, 0, stream>>>(h1T, Wzl, bzl, Wzs, bzs,
                                      eps_z + (size_t)t * B * Z, z0T, acc);
    }

    if (!pathA && hasTh) {
      // immediate theta tail for step t-1
      k_lin<<<gLin, 256, 0, stream>>>(th_new, H, 0, nullptr, 0, th_W1, th_b1, g1T, 0, 1);
      dim3 gy((F + 3) / 4, B / 64, 1);
      k_yhead<<<gy, 256, 0, stream>>>(g1T, 0, t - 1, Wyl, byl, Wys, bys,
                                      xT, out, acc + 1);
    }
  }

  if (pathA) {
    // deferred theta tail, chunked over timesteps (MLP2 composed into y head)
    for (int c = 0; c < L / TC; ++c) {
      const float* thh = th_all + (size_t)(c * TC + 1) * HB;
      dim3 g1(D / 8, B / 64, TC);
      k_lin<<<g1, 256, 0, stream>>>(thh, H, HB, nullptr, 0, th_W1, th_b1, g1_c, DB, 1);
      dim3 gy((F + 3) / 4, B / 64, TC);
      k_yhead<<<gy, 256, 0, stream>>>(g1_c, DB, c * TC, Wyl, byl, Wys, bys,
                                      xT, out, acc + 1);
    }
  }

  k_finalize<<<1, 1, 0, stream>>>(acc, out);
}